// Round 1
// baseline (311.194 us; speedup 1.0000x reference)
//
#include <hip/hip_runtime.h>

#define FDIM 32
#define BSH 7                 // 128 nodes per bucket
#define BNODES 128
#define NBMAX 1024            // max buckets (N <= 131072)
#define CHUNK 8192            // edges per partition chunk (391 chunks at E=3.2M)
#define NCMAX 512             // max chunks (E <= 4.19M)
#define CAP 4608              // per-bucket record cap (mean 4096, +8 sigma)
#define NGRAN 160             // LUT granules (CAP/32 = 144, padded)

typedef unsigned int u32;
typedef unsigned short u16;

#define BFLO(u) __uint_as_float((u) << 16)
#define BFHI(u) __uint_as_float((u) & 0xFFFF0000u)

__device__ __forceinline__ void acc8(float4& p0, float4& p1, float w, uint4 h) {
    p0.x = fmaf(w, BFLO(h.x), p0.x);
    p0.y = fmaf(w, BFHI(h.x), p0.y);
    p0.z = fmaf(w, BFLO(h.y), p0.z);
    p0.w = fmaf(w, BFHI(h.y), p0.w);
    p1.x = fmaf(w, BFLO(h.z), p1.x);
    p1.y = fmaf(w, BFHI(h.z), p1.y);
    p1.z = fmaf(w, BFLO(h.w), p1.z);
    p1.w = fmaf(w, BFHI(h.w), p1.w);
}

// ---------------- k1b: partition + global degree atomics + transposed offsets ----------------
__global__ __launch_bounds__(1024) void k1b(const int* __restrict__ srcs,
                                            const int* __restrict__ dsts,
                                            const float* __restrict__ ew,
                                            u32* __restrict__ offsT,
                                            u32* __restrict__ rkey,
                                            float* __restrict__ rw,
                                            u32* __restrict__ deg,
                                            int E, int NB, int nch) {
    __shared__ u32 lh[NBMAX];
    __shared__ u32 wsum[16];
    int t = threadIdx.x, c = blockIdx.x;
    int base = c * CHUNK;
    int end = base + CHUNK; if (end > E) end = E;
    int nloc = end - base;
    for (int i = t; i < NB; i += 1024) lh[i] = 0u;
    __syncthreads();
    int i0 = t * 8;
    bool full = (i0 + 8 <= nloc);
    int sv[8];
    if (full) {
        int4 a = ((const int4*)(srcs + base))[t * 2];
        int4 bb = ((const int4*)(srcs + base))[t * 2 + 1];
        sv[0] = a.x; sv[1] = a.y; sv[2] = a.z; sv[3] = a.w;
        sv[4] = bb.x; sv[5] = bb.y; sv[6] = bb.z; sv[7] = bb.w;
#pragma unroll
        for (int k = 0; k < 8; ++k) {
            atomicAdd(&lh[sv[k] >> BSH], 1u);
            atomicAdd(&deg[sv[k]], 1u);          // fire-and-forget global degree
        }
    } else {
        for (int i = i0; i < i0 + 8 && i < nloc; ++i) {
            int s = srcs[base + i];
            sv[i - i0] = s;
            atomicAdd(&lh[s >> BSH], 1u);
            atomicAdd(&deg[s], 1u);
        }
    }
    __syncthreads();
    // shfl-based inclusive scan over NB bucket counts (2 barriers vs 20)
    int lane = t & 63, w = t >> 6;
    u32 v = (t < NB) ? lh[t] : 0u;
    u32 inc = v;
#pragma unroll
    for (int d = 1; d < 64; d <<= 1) {
        u32 o = __shfl_up(inc, (unsigned)d, 64);
        if (lane >= d) inc += o;
    }
    if (lane == 63) wsum[w] = inc;
    __syncthreads();
    u32 woff = 0;
    for (int i = 0; i < w; ++i) woff += wsum[i];
    inc += woff;
    u32 ex = inc - v;
    if (t < NB) { offsT[(size_t)t * nch + c] = ex; lh[t] = ex; }
    if (t == 0) offsT[(size_t)NB * nch + c] = (u32)nloc;
    __syncthreads();
    if (full) {
        int4 d0 = ((const int4*)(dsts + base))[t * 2];
        int4 d1 = ((const int4*)(dsts + base))[t * 2 + 1];
        float4 w0 = ((const float4*)(ew + base))[t * 2];
        float4 w1 = ((const float4*)(ew + base))[t * 2 + 1];
        int dv[8] = { d0.x, d0.y, d0.z, d0.w, d1.x, d1.y, d1.z, d1.w };
        float wv[8] = { w0.x, w0.y, w0.z, w0.w, w1.x, w1.y, w1.z, w1.w };
#pragma unroll
        for (int k = 0; k < 8; ++k) {
            int s = sv[k];
            u32 pos = atomicAdd(&lh[s >> BSH], 1u);
            rkey[(size_t)base + pos] = ((u32)(s & (BNODES - 1)) << 17) | (u32)dv[k];
            rw[(size_t)base + pos] = wv[k];
        }
    } else {
        for (int i = i0; i < i0 + 8 && i < nloc; ++i) {
            int s = sv[i - i0];
            u32 pos = atomicAdd(&lh[s >> BSH], 1u);
            rkey[(size_t)base + pos] = ((u32)(s & (BNODES - 1)) << 17) | (u32)dsts[base + i];
            rw[(size_t)base + pos] = ew[base + i];
        }
    }
}

// ---------------- k_nh: slim GEMM + nodemeta from deg[] (no rkey walk) ----------------
__global__ __launch_bounds__(512) void k_nh(const float* __restrict__ feat,
                                            const float* __restrict__ kern,
                                            const u32* __restrict__ deg,
                                            u16* __restrict__ hsb,
                                            u32* __restrict__ nodemeta,
                                            int N) {
    __shared__ float skern[FDIM * FDIM];
    __shared__ float sfeat[BNODES * FDIM];
    __shared__ float lnorm[BNODES];
    __shared__ u32 ws2[2];
    int b = blockIdx.x, t = threadIdx.x;
    for (int i = t; i < FDIM * FDIM; i += 512) skern[i] = kern[i];
    int base_n = b << BSH;
    int base_nf = base_n * FDIM;
    int lim = N * FDIM - base_nf; if (lim > BNODES * FDIM) lim = BNODES * FDIM;
    for (int i = t; i < lim; i += 512) sfeat[i] = feat[base_nf + i];
    u32 d = 0u, pad = 0u, inc = 0u;
    if (t < BNODES) {
        int n = base_n + t;
        d = (n < N) ? deg[n] : 0u;
        pad = (d + 1u) & ~1u;                    // even-pad for b128 gather alignment
        inc = pad;
    }
    if (t < 128) {
#pragma unroll
        for (int dd = 1; dd < 64; dd <<= 1) {
            u32 o = __shfl_up(inc, (unsigned)dd, 64);
            if ((t & 63) >= dd) inc += o;
        }
        if ((t & 63) == 63) ws2[t >> 6] = inc;
    }
    __syncthreads();
    if (t < 128) {
        if (t >= 64) inc += ws2[0];
        u32 ex = inc - pad;
        lnorm[t] = rsqrtf(fmaxf((float)d, 1.0f));
        int n = base_n + t;
        if (n < N) nodemeta[n] = ex | (d << 16);
    }
    __syncthreads();
    int f = t & 31, g8 = t >> 5;
    for (int k8 = 0; k8 < 8; ++k8) {
        int nl = g8 * 8 + k8;
        int n = base_n + nl;
        if (n >= N) continue;
        float acc = 0.f;
#pragma unroll
        for (int k = 0; k < FDIM; ++k)
            acc = fmaf(sfeat[nl * FDIM + k], skern[k * FDIM + f], acc);
        float x = lnorm[nl] * acc;
        u32 u = __float_as_uint(x);
        u = (u + 0x7FFFu + ((u >> 16) & 1u)) >> 16;   // RNE f32 -> bf16
        hsb[(size_t)n * FDIM + f] = (u16)u;
    }
}

// ---------------- k2: node-sort scatter + 4-lane/node uint4 gather ----------------
__global__ __launch_bounds__(512) void k2(const u32* __restrict__ rkey,
                                          const float* __restrict__ rw,
                                          const u32* __restrict__ offsT,
                                          const u32* __restrict__ nodemeta,
                                          const u16* __restrict__ hsb,
                                          const float* __restrict__ bias,
                                          float* __restrict__ out,
                                          int N, int NB, int nch) {
    __shared__ uint2 ssrec[CAP];            // 36 KB: (dst, w) node-sorted
    __shared__ u32 sstart[NCMAX];
    __shared__ u32 ltmp[NCMAX];
    __shared__ u16 lut[NGRAN];
    __shared__ u32 loff[BNODES];
    __shared__ u32 lcnt[BNODES];
    __shared__ u32 lcur[BNODES];
    __shared__ u32 snode[BNODES];
    __shared__ u32 lbin[128];
    __shared__ u32 wsum[8];
    __shared__ u32 ws2[2];
    int b = blockIdx.x, t = threadIdx.x;
    int base_n = b << BSH;
    if (t < BNODES) {
        int n = base_n + t;
        u32 m = (n < N) ? nodemeta[n] : 0u;
        loff[t] = m & 0xFFFFu;
        lcnt[t] = m >> 16;
        lcur[t] = m & 0xFFFFu;
    }
    if (t < 128) lbin[t] = 0u;
    u32 rl = 0u;
    if (t < nch) {
        u32 s0 = offsT[(size_t)b * nch + t];         // coalesced row read
        u32 s1 = offsT[(size_t)(b + 1) * nch + t];   // coalesced row read
        sstart[t] = s0;
        rl = s1 - s0;
    }
    // shfl-based inclusive scan of per-chunk run lengths (2 barriers vs 18)
    int lane = t & 63, w = t >> 6;
    u32 inc = rl;
#pragma unroll
    for (int d = 1; d < 64; d <<= 1) {
        u32 o = __shfl_up(inc, (unsigned)d, 64);
        if (lane >= d) inc += o;
    }
    if (lane == 63) wsum[w] = inc;
    __syncthreads();
    u32 woff = 0;
    for (int i = 0; i < w; ++i) woff += wsum[i];
    inc += woff;
    ltmp[t] = inc;
    __syncthreads();
    u32 tot = ltmp[nch - 1];
    if (tot > CAP) tot = CAP;
    // granule->run LUT: lut[k] = first run r with ltmp[r] > 32k
    if (t < NGRAN && (u32)(t << 5) < tot) {
        u32 target = (u32)t << 5;
        int lo = 0, hi = nch - 1;
        while (lo < hi) { int m = (lo + hi) >> 1; if (ltmp[m] > target) hi = m; else lo = m + 1; }
        lut[t] = (u16)lo;
    }
    __syncthreads();
    // streaming node-sort scatter: coalesced rkey/rw loads -> node-contiguous LDS
    for (u32 g2 = t; g2 < tot; g2 += 512) {
        int r = lut[g2 >> 5];
        while (ltmp[r] <= g2) ++r;
        u32 pl0 = r ? ltmp[r - 1] : 0u;
        size_t idx = (size_t)r * CHUNK + sstart[r] + (g2 - pl0);
        u32 key = rkey[idx];
        float wv = rw[idx];
        u32 sl = key >> 17;
        u32 pos = atomicAdd(&lcur[sl], 1u);
        if (pos < CAP) ssrec[pos] = make_uint2(key & 0x1FFFFu, __float_as_uint(wv));
    }
    // degree counting-sort (128 bins) for wave load balance — shfl scan
    if (t < BNODES) {
        u32 len = lcnt[t];
        atomicAdd(&lbin[len > 127u ? 127u : len], 1u);
    }
    __syncthreads();
    u32 bv_ = 0u, binc = 0u;
    if (t < 128) {
        bv_ = lbin[t];
        binc = bv_;
#pragma unroll
        for (int dd = 1; dd < 64; dd <<= 1) {
            u32 o = __shfl_up(binc, (unsigned)dd, 64);
            if ((t & 63) >= dd) binc += o;
        }
        if ((t & 63) == 63) ws2[t >> 6] = binc;
    }
    __syncthreads();
    if (t < 128) {
        if (t >= 64) binc += ws2[0];
        lbin[t] = binc - bv_;                        // exclusive
    }
    __syncthreads();
    if (t < BNODES) {
        u32 len = lcnt[t];
        u32 pos = atomicAdd(&lbin[len > 127u ? 127u : len], 1u);
        snode[pos] = (u32)t;
    }
    __syncthreads();
    // gather: 128 groups of 4 lanes; lane l = features 8l..8l+7 (uint4 = 16B = full slice)
    int l = t & 3, g = t >> 2;
    u32 nl = snode[g];
    int n = base_n + (int)nl;
    u32 off = loff[nl];                  // even -> 16 B aligned
    u32 len = lcnt[nl];
    float ns = rsqrtf(fmaxf((float)len, 1.0f));
    const uint4* hp4 = (const uint4*)hsb;           // row n: hp4[n*4 + l]
    float4 bv0 = ((const float4*)bias)[2 * l];
    float4 bv1 = ((const float4*)bias)[2 * l + 1];
    float4 x0 = make_float4(0.f, 0.f, 0.f, 0.f), x1 = make_float4(0.f, 0.f, 0.f, 0.f);
    float4 y0 = make_float4(0.f, 0.f, 0.f, 0.f), y1 = make_float4(0.f, 0.f, 0.f, 0.f);
    u32 j = 0;
    for (; j + 4 <= len; j += 4) {
        uint4 q0 = *(const uint4*)(ssrec + off + j);       // rec j, j+1
        uint4 q1 = *(const uint4*)(ssrec + off + j + 2);   // rec j+2, j+3
        uint4 h0 = hp4[(size_t)q0.x * 4 + l];              // 4 gathers in flight
        uint4 h1 = hp4[(size_t)q0.z * 4 + l];
        uint4 h2 = hp4[(size_t)q1.x * 4 + l];
        uint4 h3 = hp4[(size_t)q1.z * 4 + l];
        float w0 = __uint_as_float(q0.y), w1 = __uint_as_float(q0.w);
        float w2 = __uint_as_float(q1.y), w3 = __uint_as_float(q1.w);
        acc8(x0, x1, w0, h0);
        acc8(y0, y1, w1, h1);
        acc8(x0, x1, w2, h2);
        acc8(y0, y1, w3, h3);
    }
    for (; j < len; ++j) {
        uint2 q = ssrec[off + j];
        uint4 h = hp4[(size_t)q.x * 4 + l];
        acc8(x0, x1, __uint_as_float(q.y), h);
    }
    if (n < N) {
        float4 r0, r1;
        r0.x = fmaf(ns, x0.x + y0.x, bv0.x);
        r0.y = fmaf(ns, x0.y + y0.y, bv0.y);
        r0.z = fmaf(ns, x0.z + y0.z, bv0.z);
        r0.w = fmaf(ns, x0.w + y0.w, bv0.w);
        r1.x = fmaf(ns, x1.x + y1.x, bv1.x);
        r1.y = fmaf(ns, x1.y + y1.y, bv1.y);
        r1.z = fmaf(ns, x1.z + y1.z, bv1.z);
        r1.w = fmaf(ns, x1.w + y1.w, bv1.w);
        ((float4*)(out + (size_t)n * FDIM))[2 * l] = r0;
        ((float4*)(out + (size_t)n * FDIM))[2 * l + 1] = r1;
    }
}

extern "C" void kernel_launch(void* const* d_in, const int* in_sizes, int n_in,
                              void* d_out, int out_size, void* d_ws, size_t ws_size,
                              hipStream_t stream) {
    const float* feat = (const float*)d_in[0];
    const int*   srcs = (const int*)d_in[1];
    const int*   dsts = (const int*)d_in[2];
    const float* ew   = (const float*)d_in[3];
    const float* kern = (const float*)d_in[4];
    const float* bias = (const float*)d_in[5];
    float* out = (float*)d_out;

    int N = in_sizes[0] / FDIM;
    int E = in_sizes[1];
    int NB = (N + BNODES - 1) >> BSH;        // 782 for N=100000; <= NBMAX
    int nchunks = (E + CHUNK - 1) / CHUNK;   // 391; <= NCMAX

    // workspace layout (~34.4 MB)
    char* w = (char*)d_ws;
    u16* hsb      = (u16*)w;   w += (((size_t)N * FDIM * sizeof(u16) + 15) & ~15ull);  // 6.4 MB
    u32* rkey     = (u32*)w;   w += (size_t)nchunks * CHUNK * sizeof(u32);             // 12.8 MB
    float* rw     = (float*)w; w += (size_t)nchunks * CHUNK * sizeof(float);           // 12.8 MB
    u32* offsT    = (u32*)w;   w += (size_t)(NB + 1) * nchunks * sizeof(u32);          // 1.2 MB (transposed)
    u32* nodemeta = (u32*)w;   w += (size_t)N * sizeof(u32);                           // 0.4 MB
    u32* deg      = (u32*)w;   w += (size_t)N * sizeof(u32);                           // 0.4 MB

    hipMemsetAsync(deg, 0, (size_t)N * sizeof(u32), stream);
    k1b<<<nchunks, 1024, 0, stream>>>(srcs, dsts, ew, offsT, rkey, rw, deg, E, NB, nchunks);
    k_nh<<<NB, 512, 0, stream>>>(feat, kern, deg, hsb, nodemeta, N);
    k2<<<NB, 512, 0, stream>>>(rkey, rw, offsT, nodemeta, hsb, bias, out, N, NB, nchunks);
}

// Round 2
// 206.908 us; speedup vs baseline: 1.5040x; 1.5040x over previous
//
#include <hip/hip_runtime.h>

#define FDIM 32
#define BSH 7                 // 128 nodes per bucket
#define BNODES 128
#define NBMAX 1024            // max buckets (N <= 131072)
#define CHUNK 8192            // edges per partition chunk (391 chunks at E=3.2M)
#define NCMAX 512             // max chunks (E <= 4.19M)
#define CAP 4608              // per-bucket record cap (mean 4096, +8 sigma)
#define NGRAN 160             // LUT granules (CAP/32 = 144, padded)

typedef unsigned int u32;
typedef unsigned short u16;

#define BFLO(u) __uint_as_float((u) << 16)
#define BFHI(u) __uint_as_float((u) & 0xFFFF0000u)

__device__ __forceinline__ void acc8(float4& p0, float4& p1, float w, uint4 h) {
    p0.x = fmaf(w, BFLO(h.x), p0.x);
    p0.y = fmaf(w, BFHI(h.x), p0.y);
    p0.z = fmaf(w, BFLO(h.y), p0.z);
    p0.w = fmaf(w, BFHI(h.y), p0.w);
    p1.x = fmaf(w, BFLO(h.z), p1.x);
    p1.y = fmaf(w, BFHI(h.z), p1.y);
    p1.z = fmaf(w, BFLO(h.w), p1.z);
    p1.w = fmaf(w, BFHI(h.w), p1.w);
}

// ---------------- k1b: private-region partition, transposed offsets, shfl scan ----------------
// NO global deg atomics (round-1 lesson: device-scope atomics resolve at the fabric,
// 3.2M RMWs = 177MB writes + 90us — deg comes from k_nh's LDS-histogram walk instead)
__global__ __launch_bounds__(1024) void k1b(const int* __restrict__ srcs,
                                            const int* __restrict__ dsts,
                                            const float* __restrict__ ew,
                                            u32* __restrict__ offsT,
                                            u32* __restrict__ rkey,
                                            float* __restrict__ rw,
                                            int E, int NB, int nch) {
    __shared__ u32 lh[NBMAX];
    __shared__ u32 wsum[16];
    int t = threadIdx.x, c = blockIdx.x;
    int base = c * CHUNK;
    int end = base + CHUNK; if (end > E) end = E;
    int nloc = end - base;
    for (int i = t; i < NB; i += 1024) lh[i] = 0u;
    __syncthreads();
    int i0 = t * 8;
    bool full = (i0 + 8 <= nloc);
    int sv[8];
    if (full) {
        int4 a = ((const int4*)(srcs + base))[t * 2];
        int4 bb = ((const int4*)(srcs + base))[t * 2 + 1];
        sv[0] = a.x; sv[1] = a.y; sv[2] = a.z; sv[3] = a.w;
        sv[4] = bb.x; sv[5] = bb.y; sv[6] = bb.z; sv[7] = bb.w;
#pragma unroll
        for (int k = 0; k < 8; ++k) atomicAdd(&lh[sv[k] >> BSH], 1u);
    } else {
        for (int i = i0; i < i0 + 8 && i < nloc; ++i) {
            int s = srcs[base + i];
            sv[i - i0] = s;
            atomicAdd(&lh[s >> BSH], 1u);
        }
    }
    __syncthreads();
    // shfl-based inclusive scan over NB bucket counts (2 barriers vs 20)
    int lane = t & 63, w = t >> 6;
    u32 v = (t < NB) ? lh[t] : 0u;
    u32 inc = v;
#pragma unroll
    for (int d = 1; d < 64; d <<= 1) {
        u32 o = __shfl_up(inc, (unsigned)d, 64);
        if (lane >= d) inc += o;
    }
    if (lane == 63) wsum[w] = inc;
    __syncthreads();
    u32 woff = 0;
    for (int i = 0; i < w; ++i) woff += wsum[i];
    inc += woff;
    u32 ex = inc - v;
    if (t < NB) { offsT[(size_t)t * nch + c] = ex; lh[t] = ex; }
    if (t == 0) offsT[(size_t)NB * nch + c] = (u32)nloc;
    __syncthreads();
    if (full) {
        int4 d0 = ((const int4*)(dsts + base))[t * 2];
        int4 d1 = ((const int4*)(dsts + base))[t * 2 + 1];
        float4 w0 = ((const float4*)(ew + base))[t * 2];
        float4 w1 = ((const float4*)(ew + base))[t * 2 + 1];
        int dv[8] = { d0.x, d0.y, d0.z, d0.w, d1.x, d1.y, d1.z, d1.w };
        float wv[8] = { w0.x, w0.y, w0.z, w0.w, w1.x, w1.y, w1.z, w1.w };
#pragma unroll
        for (int k = 0; k < 8; ++k) {
            int s = sv[k];
            u32 pos = atomicAdd(&lh[s >> BSH], 1u);
            rkey[(size_t)base + pos] = ((u32)(s & (BNODES - 1)) << 17) | (u32)dv[k];
            rw[(size_t)base + pos] = wv[k];
        }
    } else {
        for (int i = i0; i < i0 + 8 && i < nloc; ++i) {
            int s = sv[i - i0];
            u32 pos = atomicAdd(&lh[s >> BSH], 1u);
            rkey[(size_t)base + pos] = ((u32)(s & (BNODES - 1)) << 17) | (u32)dsts[base + i];
            rw[(size_t)base + pos] = ew[base + i];
        }
    }
}

// ---------------- k_nh: LUT-walk key histogram (LDS atomics) -> nodemeta + bf16 hs ----------------
__global__ __launch_bounds__(512) void k_nh(const u32* __restrict__ rkey,
                                            const u32* __restrict__ offsT,
                                            const float* __restrict__ feat,
                                            const float* __restrict__ kern,
                                            u16* __restrict__ hsb,
                                            u32* __restrict__ nodemeta,
                                            int N, int NB, int nch) {
    __shared__ float skern[FDIM * FDIM];
    __shared__ float sfeat[BNODES * FDIM];
    __shared__ u32 sstart[NCMAX];
    __shared__ u32 ltmp[NCMAX];
    __shared__ u16 lut[NGRAN];
    __shared__ u32 lcnt[BNODES];
    __shared__ float lnorm[BNODES];
    __shared__ u32 wsum[8];
    __shared__ u32 ws2[2];
    int b = blockIdx.x, t = threadIdx.x;
    for (int i = t; i < FDIM * FDIM; i += 512) skern[i] = kern[i];
    int base_n = b << BSH;
    int base_nf = base_n * FDIM;
    int lim = N * FDIM - base_nf; if (lim > BNODES * FDIM) lim = BNODES * FDIM;
    for (int i = t; i < lim; i += 512) sfeat[i] = feat[base_nf + i];
    if (t < BNODES) lcnt[t] = 0u;
    u32 rl = 0u;
    if (t < nch) {
        u32 s0 = offsT[(size_t)b * nch + t];         // coalesced row read
        u32 s1 = offsT[(size_t)(b + 1) * nch + t];   // coalesced row read
        sstart[t] = s0;
        rl = s1 - s0;
    }
    // shfl-based inclusive scan of per-chunk run lengths (2 barriers vs 18)
    int lane = t & 63, w = t >> 6;
    u32 inc = rl;
#pragma unroll
    for (int d = 1; d < 64; d <<= 1) {
        u32 o = __shfl_up(inc, (unsigned)d, 64);
        if (lane >= d) inc += o;
    }
    if (lane == 63) wsum[w] = inc;
    __syncthreads();
    u32 woff = 0;
    for (int i = 0; i < w; ++i) woff += wsum[i];
    inc += woff;
    ltmp[t] = inc;
    __syncthreads();
    u32 tot = ltmp[nch - 1];
    if (tot > CAP) tot = CAP;
    // granule->run LUT: lut[k] = first run r with ltmp[r] > 32k
    if (t < NGRAN && (u32)(t << 5) < tot) {
        u32 target = (u32)t << 5;
        int lo = 0, hi = nch - 1;
        while (lo < hi) { int m = (lo + hi) >> 1; if (ltmp[m] > target) hi = m; else lo = m + 1; }
        lut[t] = (u16)lo;
    }
    __syncthreads();
    for (u32 g = t; g < tot; g += 512) {
        int r = lut[g >> 5];
        while (ltmp[r] <= g) ++r;
        u32 pl0 = r ? ltmp[r - 1] : 0u;
        u32 key = rkey[(size_t)r * CHUNK + sstart[r] + (g - pl0)];
        atomicAdd(&lcnt[key >> 17], 1u);
    }
    __syncthreads();
    // nodemeta: even-padded exclusive offsets (shfl scan over 128)
    u32 d = 0u, pad = 0u, inc2 = 0u;
    if (t < BNODES) {
        d = lcnt[t];
        pad = (d + 1u) & ~1u;                        // even-pad for b128 gather alignment
        inc2 = pad;
    }
    if (t < 128) {
#pragma unroll
        for (int dd = 1; dd < 64; dd <<= 1) {
            u32 o = __shfl_up(inc2, (unsigned)dd, 64);
            if ((t & 63) >= dd) inc2 += o;
        }
        if ((t & 63) == 63) ws2[t >> 6] = inc2;
    }
    __syncthreads();
    if (t < 128) {
        if (t >= 64) inc2 += ws2[0];
        u32 ex = inc2 - pad;
        lnorm[t] = rsqrtf(fmaxf((float)d, 1.0f));
        int n = base_n + t;
        if (n < N) nodemeta[n] = ex | (d << 16);
    }
    __syncthreads();
    int f = t & 31, g8 = t >> 5;
    for (int k8 = 0; k8 < 8; ++k8) {
        int nl = g8 * 8 + k8;
        int n = base_n + nl;
        if (n >= N) continue;
        float acc = 0.f;
#pragma unroll
        for (int k = 0; k < FDIM; ++k)
            acc = fmaf(sfeat[nl * FDIM + k], skern[k * FDIM + f], acc);
        float x = lnorm[nl] * acc;
        u32 u = __float_as_uint(x);
        u = (u + 0x7FFFu + ((u >> 16) & 1u)) >> 16;   // RNE f32 -> bf16
        hsb[(size_t)n * FDIM + f] = (u16)u;
    }
}

// ---------------- k2: node-sort scatter + 4-lane/node uint4 gather ----------------
__global__ __launch_bounds__(512) void k2(const u32* __restrict__ rkey,
                                          const float* __restrict__ rw,
                                          const u32* __restrict__ offsT,
                                          const u32* __restrict__ nodemeta,
                                          const u16* __restrict__ hsb,
                                          const float* __restrict__ bias,
                                          float* __restrict__ out,
                                          int N, int NB, int nch) {
    __shared__ uint2 ssrec[CAP];            // 36 KB: (dst, w) node-sorted
    __shared__ u32 sstart[NCMAX];
    __shared__ u32 ltmp[NCMAX];
    __shared__ u16 lut[NGRAN];
    __shared__ u32 loff[BNODES];
    __shared__ u32 lcnt[BNODES];
    __shared__ u32 lcur[BNODES];
    __shared__ u32 snode[BNODES];
    __shared__ u32 lbin[128];
    __shared__ u32 wsum[8];
    __shared__ u32 ws2[2];
    int b = blockIdx.x, t = threadIdx.x;
    int base_n = b << BSH;
    if (t < BNODES) {
        int n = base_n + t;
        u32 m = (n < N) ? nodemeta[n] : 0u;
        loff[t] = m & 0xFFFFu;
        lcnt[t] = m >> 16;
        lcur[t] = m & 0xFFFFu;
    }
    if (t < 128) lbin[t] = 0u;
    u32 rl = 0u;
    if (t < nch) {
        u32 s0 = offsT[(size_t)b * nch + t];         // coalesced row read
        u32 s1 = offsT[(size_t)(b + 1) * nch + t];   // coalesced row read
        sstart[t] = s0;
        rl = s1 - s0;
    }
    // shfl-based inclusive scan of per-chunk run lengths
    int lane = t & 63, w = t >> 6;
    u32 inc = rl;
#pragma unroll
    for (int d = 1; d < 64; d <<= 1) {
        u32 o = __shfl_up(inc, (unsigned)d, 64);
        if (lane >= d) inc += o;
    }
    if (lane == 63) wsum[w] = inc;
    __syncthreads();
    u32 woff = 0;
    for (int i = 0; i < w; ++i) woff += wsum[i];
    inc += woff;
    ltmp[t] = inc;
    __syncthreads();
    u32 tot = ltmp[nch - 1];
    if (tot > CAP) tot = CAP;
    // granule->run LUT: lut[k] = first run r with ltmp[r] > 32k
    if (t < NGRAN && (u32)(t << 5) < tot) {
        u32 target = (u32)t << 5;
        int lo = 0, hi = nch - 1;
        while (lo < hi) { int m = (lo + hi) >> 1; if (ltmp[m] > target) hi = m; else lo = m + 1; }
        lut[t] = (u16)lo;
    }
    __syncthreads();
    // streaming node-sort scatter: coalesced rkey/rw loads -> node-contiguous LDS
    for (u32 g2 = t; g2 < tot; g2 += 512) {
        int r = lut[g2 >> 5];
        while (ltmp[r] <= g2) ++r;
        u32 pl0 = r ? ltmp[r - 1] : 0u;
        size_t idx = (size_t)r * CHUNK + sstart[r] + (g2 - pl0);
        u32 key = rkey[idx];
        float wv = rw[idx];
        u32 sl = key >> 17;
        u32 pos = atomicAdd(&lcur[sl], 1u);
        if (pos < CAP) ssrec[pos] = make_uint2(key & 0x1FFFFu, __float_as_uint(wv));
    }
    // degree counting-sort (128 bins) for wave load balance — shfl scan
    if (t < BNODES) {
        u32 len = lcnt[t];
        atomicAdd(&lbin[len > 127u ? 127u : len], 1u);
    }
    __syncthreads();
    u32 bv_ = 0u, binc = 0u;
    if (t < 128) {
        bv_ = lbin[t];
        binc = bv_;
#pragma unroll
        for (int dd = 1; dd < 64; dd <<= 1) {
            u32 o = __shfl_up(binc, (unsigned)dd, 64);
            if ((t & 63) >= dd) binc += o;
        }
        if ((t & 63) == 63) ws2[t >> 6] = binc;
    }
    __syncthreads();
    if (t < 128) {
        if (t >= 64) binc += ws2[0];
        lbin[t] = binc - bv_;                        // exclusive
    }
    __syncthreads();
    if (t < BNODES) {
        u32 len = lcnt[t];
        u32 pos = atomicAdd(&lbin[len > 127u ? 127u : len], 1u);
        snode[pos] = (u32)t;
    }
    __syncthreads();
    // gather: 128 groups of 4 lanes; lane l = features 8l..8l+7 (uint4 = 16B = full slice)
    int l = t & 3, g = t >> 2;
    u32 nl = snode[g];
    int n = base_n + (int)nl;
    u32 off = loff[nl];                  // even -> 16 B aligned
    u32 len = lcnt[nl];
    float ns = rsqrtf(fmaxf((float)len, 1.0f));
    const uint4* hp4 = (const uint4*)hsb;           // row n: hp4[n*4 + l]
    float4 bv0 = ((const float4*)bias)[2 * l];
    float4 bv1 = ((const float4*)bias)[2 * l + 1];
    float4 x0 = make_float4(0.f, 0.f, 0.f, 0.f), x1 = make_float4(0.f, 0.f, 0.f, 0.f);
    float4 y0 = make_float4(0.f, 0.f, 0.f, 0.f), y1 = make_float4(0.f, 0.f, 0.f, 0.f);
    u32 j = 0;
    for (; j + 4 <= len; j += 4) {
        uint4 q0 = *(const uint4*)(ssrec + off + j);       // rec j, j+1
        uint4 q1 = *(const uint4*)(ssrec + off + j + 2);   // rec j+2, j+3
        uint4 h0 = hp4[(size_t)q0.x * 4 + l];              // 4 gathers in flight
        uint4 h1 = hp4[(size_t)q0.z * 4 + l];
        uint4 h2 = hp4[(size_t)q1.x * 4 + l];
        uint4 h3 = hp4[(size_t)q1.z * 4 + l];
        float w0 = __uint_as_float(q0.y), w1 = __uint_as_float(q0.w);
        float w2 = __uint_as_float(q1.y), w3 = __uint_as_float(q1.w);
        acc8(x0, x1, w0, h0);
        acc8(y0, y1, w1, h1);
        acc8(x0, x1, w2, h2);
        acc8(y0, y1, w3, h3);
    }
    for (; j < len; ++j) {
        uint2 q = ssrec[off + j];
        uint4 h = hp4[(size_t)q.x * 4 + l];
        acc8(x0, x1, __uint_as_float(q.y), h);
    }
    if (n < N) {
        float4 r0, r1;
        r0.x = fmaf(ns, x0.x + y0.x, bv0.x);
        r0.y = fmaf(ns, x0.y + y0.y, bv0.y);
        r0.z = fmaf(ns, x0.z + y0.z, bv0.z);
        r0.w = fmaf(ns, x0.w + y0.w, bv0.w);
        r1.x = fmaf(ns, x1.x + y1.x, bv1.x);
        r1.y = fmaf(ns, x1.y + y1.y, bv1.y);
        r1.z = fmaf(ns, x1.z + y1.z, bv1.z);
        r1.w = fmaf(ns, x1.w + y1.w, bv1.w);
        ((float4*)(out + (size_t)n * FDIM))[2 * l] = r0;
        ((float4*)(out + (size_t)n * FDIM))[2 * l + 1] = r1;
    }
}

extern "C" void kernel_launch(void* const* d_in, const int* in_sizes, int n_in,
                              void* d_out, int out_size, void* d_ws, size_t ws_size,
                              hipStream_t stream) {
    const float* feat = (const float*)d_in[0];
    const int*   srcs = (const int*)d_in[1];
    const int*   dsts = (const int*)d_in[2];
    const float* ew   = (const float*)d_in[3];
    const float* kern = (const float*)d_in[4];
    const float* bias = (const float*)d_in[5];
    float* out = (float*)d_out;

    int N = in_sizes[0] / FDIM;
    int E = in_sizes[1];
    int NB = (N + BNODES - 1) >> BSH;        // 782 for N=100000; <= NBMAX
    int nchunks = (E + CHUNK - 1) / CHUNK;   // 391; <= NCMAX

    // workspace layout (~34 MB)
    char* w = (char*)d_ws;
    u16* hsb      = (u16*)w;   w += (((size_t)N * FDIM * sizeof(u16) + 15) & ~15ull);  // 6.4 MB
    u32* rkey     = (u32*)w;   w += (size_t)nchunks * CHUNK * sizeof(u32);             // 12.8 MB
    float* rw     = (float*)w; w += (size_t)nchunks * CHUNK * sizeof(float);           // 12.8 MB
    u32* offsT    = (u32*)w;   w += (size_t)(NB + 1) * nchunks * sizeof(u32);          // 1.2 MB (transposed)
    u32* nodemeta = (u32*)w;   w += (size_t)N * sizeof(u32);                           // 0.4 MB

    k1b<<<nchunks, 1024, 0, stream>>>(srcs, dsts, ew, offsT, rkey, rw, E, NB, nchunks);
    k_nh<<<NB, 512, 0, stream>>>(rkey, offsT, feat, kern, hsb, nodemeta, N, NB, nchunks);
    k2<<<NB, 512, 0, stream>>>(rkey, rw, offsT, nodemeta, hsb, bias, out, N, NB, nchunks);
}

// Round 3
// 176.077 us; speedup vs baseline: 1.7674x; 1.1751x over previous
//
#include <hip/hip_runtime.h>

#define FDIM 32
#define BSH 7                 // 128 nodes per bucket
#define BNODES 128
#define NBMAX 1024            // max buckets (N <= 131072)
#define CHUNK 8192            // edges per partition chunk (391 chunks at E=3.2M)
#define NCMAX 512             // max chunks (E <= 4.19M)
#define CAP 4608              // per-bucket record cap (mean 4096, +8 sigma)

typedef unsigned int u32;
typedef unsigned short u16;

#define BFLO(u) __uint_as_float((u) << 16)
#define BFHI(u) __uint_as_float((u) & 0xFFFF0000u)

__device__ __forceinline__ void acc8(float4& p0, float4& p1, float w, uint4 h) {
    p0.x = fmaf(w, BFLO(h.x), p0.x);
    p0.y = fmaf(w, BFHI(h.x), p0.y);
    p0.z = fmaf(w, BFLO(h.y), p0.z);
    p0.w = fmaf(w, BFHI(h.y), p0.w);
    p1.x = fmaf(w, BFLO(h.z), p1.x);
    p1.y = fmaf(w, BFHI(h.z), p1.y);
    p1.z = fmaf(w, BFLO(h.w), p1.z);
    p1.w = fmaf(w, BFHI(h.w), p1.w);
}

// ---------------- k1b: partition; rank-from-histogram (single atomic pass); uint2 rec ----------------
__global__ __launch_bounds__(1024) void k1b(const int* __restrict__ srcs,
                                            const int* __restrict__ dsts,
                                            const float* __restrict__ ew,
                                            u32* __restrict__ offsT,
                                            uint2* __restrict__ rec,
                                            int E, int NB, int nch) {
    __shared__ u32 lh[NBMAX];
    __shared__ u32 wsum[16];
    int t = threadIdx.x, c = blockIdx.x;
    int base = c * CHUNK;
    int end = base + CHUNK; if (end > E) end = E;
    int nloc = end - base;
    int i0 = t * 8;
    bool full = (i0 + 8 <= nloc);
    int sv[8], dv[8];
    float wv[8];
    u32 rk[8];
    // hoist ALL loads before the histogram (latency overlap)
    if (full) {
        int4 a  = ((const int4*)(srcs + base))[t * 2];
        int4 b2 = ((const int4*)(srcs + base))[t * 2 + 1];
        int4 d0 = ((const int4*)(dsts + base))[t * 2];
        int4 d1 = ((const int4*)(dsts + base))[t * 2 + 1];
        float4 w0 = ((const float4*)(ew + base))[t * 2];
        float4 w1 = ((const float4*)(ew + base))[t * 2 + 1];
        sv[0]=a.x; sv[1]=a.y; sv[2]=a.z; sv[3]=a.w; sv[4]=b2.x; sv[5]=b2.y; sv[6]=b2.z; sv[7]=b2.w;
        dv[0]=d0.x; dv[1]=d0.y; dv[2]=d0.z; dv[3]=d0.w; dv[4]=d1.x; dv[5]=d1.y; dv[6]=d1.z; dv[7]=d1.w;
        wv[0]=w0.x; wv[1]=w0.y; wv[2]=w0.z; wv[3]=w0.w; wv[4]=w1.x; wv[5]=w1.y; wv[6]=w1.z; wv[7]=w1.w;
    } else {
#pragma unroll
        for (int k = 0; k < 8; ++k) {
            int i = i0 + k;
            bool v = i < nloc;
            sv[k] = v ? srcs[base + i] : 0;
            dv[k] = v ? dsts[base + i] : 0;
            wv[k] = v ? ew[base + i] : 0.f;
        }
    }
    for (int i = t; i < NB; i += 1024) lh[i] = 0u;
    __syncthreads();
    if (full) {
#pragma unroll
        for (int k = 0; k < 8; ++k) rk[k] = atomicAdd(&lh[sv[k] >> BSH], 1u);
    } else {
#pragma unroll
        for (int k = 0; k < 8; ++k) {
            bool v = (i0 + k) < nloc;
            rk[k] = v ? atomicAdd(&lh[sv[k] >> BSH], 1u) : 0u;
        }
    }
    __syncthreads();
    // shfl-based inclusive scan over NB bucket counts
    int lane = t & 63, w = t >> 6;
    u32 v = (t < NB) ? lh[t] : 0u;
    u32 inc = v;
#pragma unroll
    for (int d = 1; d < 64; d <<= 1) {
        u32 o = __shfl_up(inc, (unsigned)d, 64);
        if (lane >= d) inc += o;
    }
    if (lane == 63) wsum[w] = inc;
    __syncthreads();
    u32 woff = 0;
    for (int i = 0; i < w; ++i) woff += wsum[i];
    inc += woff;
    u32 ex = inc - v;
    if (t < NB) { offsT[(size_t)t * nch + c] = ex; lh[t] = ex; }
    if (t == 0) offsT[(size_t)NB * nch + c] = (u32)nloc;
    __syncthreads();
    // atomic-free placement: pos = bucket_exclusive + rank
    if (full) {
#pragma unroll
        for (int k = 0; k < 8; ++k) {
            int s = sv[k];
            u32 pos = lh[s >> BSH] + rk[k];
            rec[(size_t)base + pos] = make_uint2(((u32)(s & (BNODES - 1)) << 17) | (u32)dv[k],
                                                __float_as_uint(wv[k]));
        }
    } else {
#pragma unroll
        for (int k = 0; k < 8; ++k) {
            if ((i0 + k) < nloc) {
                int s = sv[k];
                u32 pos = lh[s >> BSH] + rk[k];
                rec[(size_t)base + pos] = make_uint2(((u32)(s & (BNODES - 1)) << 17) | (u32)dv[k],
                                                    __float_as_uint(wv[k]));
            }
        }
    }
}

// ---------------- k_nh: runid inverse-map histogram + reg-cached GEMM -> nodemeta + bf16 hs ----------------
__global__ __launch_bounds__(512) void k_nh(const uint2* __restrict__ rec,
                                            const u32* __restrict__ offsT,
                                            const float* __restrict__ feat,
                                            const float* __restrict__ kern,
                                            u16* __restrict__ hsb,
                                            u32* __restrict__ nodemeta,
                                            int N, int NB, int nch) {
    __shared__ float skern[FDIM * FDIM];
    __shared__ float sfeat[BNODES * FDIM];
    __shared__ u32 sbase[NCMAX];
    __shared__ u16 runid[CAP];
    __shared__ u32 lcnt[BNODES];
    __shared__ float lnorm[BNODES];
    __shared__ u32 wsum[8];
    __shared__ u32 ws2[2];
    __shared__ u32 stot;
    int b = blockIdx.x, t = threadIdx.x;
    // vectorized staging of kern + bucket features
    for (int i = t; i < FDIM * FDIM / 4; i += 512) ((float4*)skern)[i] = ((const float4*)kern)[i];
    int base_n = b << BSH;
    int base_nf = base_n * FDIM;
    int lim = N * FDIM - base_nf; if (lim > BNODES * FDIM) lim = BNODES * FDIM;
    for (int i = t; i < (lim >> 2); i += 512) ((float4*)sfeat)[i] = ((const float4*)(feat + base_nf))[i];
    if (t < BNODES) lcnt[t] = 0u;
    u32 rl = 0u, s0 = 0u;
    if (t < nch) {
        s0 = offsT[(size_t)b * nch + t];             // coalesced row read
        rl = offsT[(size_t)(b + 1) * nch + t] - s0;  // coalesced row read
    }
    int lane = t & 63, w = t >> 6;
    u32 inc = rl;
#pragma unroll
    for (int d = 1; d < 64; d <<= 1) {
        u32 o = __shfl_up(inc, (unsigned)d, 64);
        if (lane >= d) inc += o;
    }
    if (lane == 63) wsum[w] = inc;
    __syncthreads();
    u32 woff = 0;
    for (int i = 0; i < w; ++i) woff += wsum[i];
    inc += woff;
    // inverse map: run r owns records [pl0, pl0+rl) -> runid[]; sbase folds all per-run consts
    if (t < nch) {
        u32 pl0 = inc - rl;
        sbase[t] = (u32)t * CHUNK + s0 - pl0;
        u32 p = pl0 < CAP ? pl0 : CAP;
        u32 e = pl0 + rl; if (e > CAP) e = CAP;
        for (; p < e; ++p) runid[p] = (u16)t;
    }
    if (t == nch - 1) stot = inc;
    __syncthreads();
    u32 tot = stot; if (tot > CAP) tot = CAP;
    // histogram: 8 statically-unrolled independent chains (no while-walk)
    {
        u32 keyv[8]; bool val[8];
#pragma unroll
        for (int i = 0; i < 8; ++i) {
            u32 g = (u32)t + ((u32)i << 9);
            val[i] = g < tot;
            keyv[i] = 0u;
            if (val[i]) {
                int r = runid[g];
                keyv[i] = rec[(size_t)(sbase[r] + g)].x;
            }
        }
#pragma unroll
        for (int i = 0; i < 8; ++i)
            if (val[i]) atomicAdd(&lcnt[keyv[i] >> 17], 1u);
        for (u32 g = (u32)t + 4096u; g < tot; g += 512u) {   // tot may exceed 4096
            int r = runid[g];
            atomicAdd(&lcnt[rec[(size_t)(sbase[r] + g)].x >> 17], 1u);
        }
    }
    __syncthreads();
    // nodemeta: even-padded exclusive offsets (shfl scan over 128)
    u32 d = 0u, pad = 0u, inc2 = 0u;
    if (t < BNODES) {
        d = lcnt[t];
        pad = (d + 1u) & ~1u;                        // even-pad for b128 gather alignment
        inc2 = pad;
    }
    if (t < 128) {
#pragma unroll
        for (int dd = 1; dd < 64; dd <<= 1) {
            u32 o = __shfl_up(inc2, (unsigned)dd, 64);
            if ((t & 63) >= dd) inc2 += o;
        }
        if ((t & 63) == 63) ws2[t >> 6] = inc2;
    }
    __syncthreads();
    if (t < 128) {
        if (t >= 64) inc2 += ws2[0];
        u32 ex = inc2 - pad;
        lnorm[t] = rsqrtf(fmaxf((float)d, 1.0f));
        int n = base_n + t;
        if (n < N) nodemeta[n] = ex | (d << 16);
    }
    __syncthreads();
    // GEMM: skern column cached in 32 registers, sfeat rows as float4
    int f = t & 31, g8 = t >> 5;
    float kc[FDIM];
#pragma unroll
    for (int k = 0; k < FDIM; ++k) kc[k] = skern[k * FDIM + f];
#pragma unroll
    for (int k8 = 0; k8 < 8; ++k8) {
        int nl = g8 * 8 + k8;
        int n = base_n + nl;
        const float4* fr = (const float4*)(sfeat + nl * FDIM);
        float4 rr[8];
#pragma unroll
        for (int q = 0; q < 8; ++q) rr[q] = fr[q];
        float acc = 0.f;
#pragma unroll
        for (int q = 0; q < 8; ++q) {
            acc = fmaf(rr[q].x, kc[4 * q + 0], acc);
            acc = fmaf(rr[q].y, kc[4 * q + 1], acc);
            acc = fmaf(rr[q].z, kc[4 * q + 2], acc);
            acc = fmaf(rr[q].w, kc[4 * q + 3], acc);
        }
        float x = lnorm[nl] * acc;
        u32 u = __float_as_uint(x);
        u = (u + 0x7FFFu + ((u >> 16) & 1u)) >> 16;   // RNE f32 -> bf16
        if (n < N) hsb[(size_t)n * FDIM + f] = (u16)u;
    }
}

// ---------------- k2: runid scatter + degree-sorted 8-wide uint4 gather ----------------
__global__ __launch_bounds__(512) void k2(const uint2* __restrict__ rec,
                                          const u32* __restrict__ offsT,
                                          const u32* __restrict__ nodemeta,
                                          const u16* __restrict__ hsb,
                                          const float* __restrict__ bias,
                                          float* __restrict__ out,
                                          int N, int NB, int nch) {
    __shared__ uint2 ssrec[CAP];            // 36 KB: (dst, w) node-sorted
    __shared__ u32 sbase[NCMAX];
    __shared__ u16 runid[CAP];
    __shared__ u32 loff[BNODES];
    __shared__ u32 lcnt[BNODES];
    __shared__ u32 lcur[BNODES];
    __shared__ u32 snode[BNODES];
    __shared__ u32 lbin[128];
    __shared__ u32 wsum[8];
    __shared__ u32 ws2[2];
    __shared__ u32 stot;
    int b = blockIdx.x, t = threadIdx.x;
    int base_n = b << BSH;
    if (t < BNODES) {
        int n = base_n + t;
        u32 m = (n < N) ? nodemeta[n] : 0u;
        loff[t] = m & 0xFFFFu;
        lcnt[t] = m >> 16;
        lcur[t] = m & 0xFFFFu;
    }
    if (t < 128) lbin[t] = 0u;
    u32 rl = 0u, s0 = 0u;
    if (t < nch) {
        s0 = offsT[(size_t)b * nch + t];
        rl = offsT[(size_t)(b + 1) * nch + t] - s0;
    }
    int lane = t & 63, w = t >> 6;
    u32 inc = rl;
#pragma unroll
    for (int d = 1; d < 64; d <<= 1) {
        u32 o = __shfl_up(inc, (unsigned)d, 64);
        if (lane >= d) inc += o;
    }
    if (lane == 63) wsum[w] = inc;
    __syncthreads();
    u32 woff = 0;
    for (int i = 0; i < w; ++i) woff += wsum[i];
    inc += woff;
    if (t < nch) {
        u32 pl0 = inc - rl;
        sbase[t] = (u32)t * CHUNK + s0 - pl0;
        u32 p = pl0 < CAP ? pl0 : CAP;
        u32 e = pl0 + rl; if (e > CAP) e = CAP;
        for (; p < e; ++p) runid[p] = (u16)t;
    }
    if (t == nch - 1) stot = inc;
    __syncthreads();
    u32 tot = stot; if (tot > CAP) tot = CAP;
    // scatter: 8 statically-unrolled independent chains; single uint2 load per record
    {
        uint2 qv[8]; bool val[8];
#pragma unroll
        for (int i = 0; i < 8; ++i) {
            u32 g = (u32)t + ((u32)i << 9);
            val[i] = g < tot;
            qv[i] = make_uint2(0u, 0u);
            if (val[i]) {
                int r = runid[g];
                qv[i] = rec[(size_t)(sbase[r] + g)];
            }
        }
#pragma unroll
        for (int i = 0; i < 8; ++i) {
            if (val[i]) {
                u32 sl = qv[i].x >> 17;
                u32 pos = atomicAdd(&lcur[sl], 1u);
                if (pos < CAP) ssrec[pos] = make_uint2(qv[i].x & 0x1FFFFu, qv[i].y);
            }
        }
        for (u32 g = (u32)t + 4096u; g < tot; g += 512u) {
            int r = runid[g];
            uint2 q = rec[(size_t)(sbase[r] + g)];
            u32 pos = atomicAdd(&lcur[q.x >> 17], 1u);
            if (pos < CAP) ssrec[pos] = make_uint2(q.x & 0x1FFFFu, q.y);
        }
    }
    // degree counting-sort (128 bins) for wave load balance — shfl scan
    if (t < BNODES) {
        u32 len = lcnt[t];
        atomicAdd(&lbin[len > 127u ? 127u : len], 1u);
    }
    __syncthreads();
    u32 bv_ = 0u, binc = 0u;
    if (t < 128) {
        bv_ = lbin[t];
        binc = bv_;
#pragma unroll
        for (int dd = 1; dd < 64; dd <<= 1) {
            u32 o = __shfl_up(binc, (unsigned)dd, 64);
            if ((t & 63) >= dd) binc += o;
        }
        if ((t & 63) == 63) ws2[t >> 6] = binc;
    }
    __syncthreads();
    if (t < 128) {
        if (t >= 64) binc += ws2[0];
        lbin[t] = binc - bv_;                        // exclusive
    }
    __syncthreads();
    if (t < BNODES) {
        u32 len = lcnt[t];
        u32 pos = atomicAdd(&lbin[len > 127u ? 127u : len], 1u);
        snode[pos] = (u32)t;
    }
    __syncthreads();
    // gather: 128 groups of 4 lanes; lane l = features 8l..8l+7; 8 records/iter (8 gathers in flight)
    int l = t & 3, g = t >> 2;
    u32 nl = snode[g];
    int n = base_n + (int)nl;
    u32 off = loff[nl];                  // even -> 16 B aligned
    u32 len = lcnt[nl];
    float ns = rsqrtf(fmaxf((float)len, 1.0f));
    const uint4* hp4 = (const uint4*)hsb;           // row n: hp4[n*4 + l]
    float4 bv0 = ((const float4*)bias)[2 * l];
    float4 bv1 = ((const float4*)bias)[2 * l + 1];
    float4 x0 = make_float4(0.f, 0.f, 0.f, 0.f), x1 = make_float4(0.f, 0.f, 0.f, 0.f);
    float4 y0 = make_float4(0.f, 0.f, 0.f, 0.f), y1 = make_float4(0.f, 0.f, 0.f, 0.f);
    u32 j = 0;
    for (; j + 8 <= len; j += 8) {
        uint4 q0 = *(const uint4*)(ssrec + off + j);
        uint4 q1 = *(const uint4*)(ssrec + off + j + 2);
        uint4 q2 = *(const uint4*)(ssrec + off + j + 4);
        uint4 q3 = *(const uint4*)(ssrec + off + j + 6);
        uint4 h0 = hp4[(size_t)q0.x * 4 + l];
        uint4 h1 = hp4[(size_t)q0.z * 4 + l];
        uint4 h2 = hp4[(size_t)q1.x * 4 + l];
        uint4 h3 = hp4[(size_t)q1.z * 4 + l];
        uint4 h4 = hp4[(size_t)q2.x * 4 + l];
        uint4 h5 = hp4[(size_t)q2.z * 4 + l];
        uint4 h6 = hp4[(size_t)q3.x * 4 + l];
        uint4 h7 = hp4[(size_t)q3.z * 4 + l];
        acc8(x0, x1, __uint_as_float(q0.y), h0);
        acc8(y0, y1, __uint_as_float(q0.w), h1);
        acc8(x0, x1, __uint_as_float(q1.y), h2);
        acc8(y0, y1, __uint_as_float(q1.w), h3);
        acc8(x0, x1, __uint_as_float(q2.y), h4);
        acc8(y0, y1, __uint_as_float(q2.w), h5);
        acc8(x0, x1, __uint_as_float(q3.y), h6);
        acc8(y0, y1, __uint_as_float(q3.w), h7);
    }
    for (; j + 4 <= len; j += 4) {
        uint4 q0 = *(const uint4*)(ssrec + off + j);
        uint4 q1 = *(const uint4*)(ssrec + off + j + 2);
        uint4 h0 = hp4[(size_t)q0.x * 4 + l];
        uint4 h1 = hp4[(size_t)q0.z * 4 + l];
        uint4 h2 = hp4[(size_t)q1.x * 4 + l];
        uint4 h3 = hp4[(size_t)q1.z * 4 + l];
        acc8(x0, x1, __uint_as_float(q0.y), h0);
        acc8(y0, y1, __uint_as_float(q0.w), h1);
        acc8(x0, x1, __uint_as_float(q1.y), h2);
        acc8(y0, y1, __uint_as_float(q1.w), h3);
    }
    for (; j < len; ++j) {
        uint2 q = ssrec[off + j];
        uint4 h = hp4[(size_t)q.x * 4 + l];
        acc8(x0, x1, __uint_as_float(q.y), h);
    }
    if (n < N) {
        float4 r0, r1;
        r0.x = fmaf(ns, x0.x + y0.x, bv0.x);
        r0.y = fmaf(ns, x0.y + y0.y, bv0.y);
        r0.z = fmaf(ns, x0.z + y0.z, bv0.z);
        r0.w = fmaf(ns, x0.w + y0.w, bv0.w);
        r1.x = fmaf(ns, x1.x + y1.x, bv1.x);
        r1.y = fmaf(ns, x1.y + y1.y, bv1.y);
        r1.z = fmaf(ns, x1.z + y1.z, bv1.z);
        r1.w = fmaf(ns, x1.w + y1.w, bv1.w);
        ((float4*)(out + (size_t)n * FDIM))[2 * l] = r0;
        ((float4*)(out + (size_t)n * FDIM))[2 * l + 1] = r1;
    }
}

extern "C" void kernel_launch(void* const* d_in, const int* in_sizes, int n_in,
                              void* d_out, int out_size, void* d_ws, size_t ws_size,
                              hipStream_t stream) {
    const float* feat = (const float*)d_in[0];
    const int*   srcs = (const int*)d_in[1];
    const int*   dsts = (const int*)d_in[2];
    const float* ew   = (const float*)d_in[3];
    const float* kern = (const float*)d_in[4];
    const float* bias = (const float*)d_in[5];
    float* out = (float*)d_out;

    int N = in_sizes[0] / FDIM;
    int E = in_sizes[1];
    int NB = (N + BNODES - 1) >> BSH;        // 782 for N=100000; <= NBMAX
    int nchunks = (E + CHUNK - 1) / CHUNK;   // 391; <= NCMAX

    // workspace layout (~33.6 MB)
    char* w = (char*)d_ws;
    u16* hsb      = (u16*)w;   w += (((size_t)N * FDIM * sizeof(u16) + 15) & ~15ull);  // 6.4 MB
    uint2* rec    = (uint2*)w; w += (size_t)nchunks * CHUNK * sizeof(uint2);           // 25.6 MB
    u32* offsT    = (u32*)w;   w += (size_t)(NB + 1) * nchunks * sizeof(u32);          // 1.2 MB (transposed)
    u32* nodemeta = (u32*)w;   w += (size_t)N * sizeof(u32);                           // 0.4 MB

    k1b<<<nchunks, 1024, 0, stream>>>(srcs, dsts, ew, offsT, rec, E, NB, nchunks);
    k_nh<<<NB, 512, 0, stream>>>(rec, offsT, feat, kern, hsb, nodemeta, N, NB, nchunks);
    k2<<<NB, 512, 0, stream>>>(rec, offsT, nodemeta, hsb, bias, out, N, NB, nchunks);
}